// Round 1
// baseline (190.835 us; speedup 1.0000x reference)
//
#include <hip/hip_runtime.h>
#include <math.h>

#define D 2048
#define EPS_COS 1e-8f
#define EPS_DEN 1e-6f
#define INV_TEMP 10.0f

// pos_pair is int64 in the reference source, but JAX x64-off makes it int32
// (and the harness spec says const int*). Hedge: accept the int32 reading iff
// it's plausible (in range, i != j — the reference guarantees i != j);
// otherwise reinterpret as int64.
__device__ __forceinline__ void get_ij(const int* __restrict__ p, int n,
                                       int& i, int& j) {
    int i32 = p[0], j32 = p[1];
    if (i32 >= 0 && i32 < n && j32 >= 0 && j32 < n && i32 != j32) {
        i = i32; j = j32; return;
    }
    const long long* p64 = (const long long*)p;
    i = (int)p64[0]; j = (int)p64[1];
}

// One block (256 threads = 4 waves) per row k.
// Each thread loads 2 float4 of x[k] and 2 float4 of x[i] (xi is L1-resident),
// accumulates dot, |xk|^2, |xi|^2; block-reduce; thread 0 writes e[k].
__global__ __launch_bounds__(256)
void row_kernel(const float* __restrict__ x, const int* __restrict__ pos,
                float* __restrict__ e_out, int n) {
    const int row = blockIdx.x;
    int i, j;
    get_ij(pos, n, i, j);

    const float4* __restrict__ xk = (const float4*)(x + (size_t)row * D);
    const float4* __restrict__ xi = (const float4*)(x + (size_t)i * D);

    float dot = 0.f, sqk = 0.f, sqi = 0.f;
    const int t = threadIdx.x;
#pragma unroll
    for (int it = 0; it < 2; ++it) {
        const int idx = t + it * 256;           // 512 float4 = 2048 floats
        float4 a = xk[idx];
        float4 b = xi[idx];
        dot = fmaf(a.x, b.x, fmaf(a.y, b.y, fmaf(a.z, b.z, fmaf(a.w, b.w, dot))));
        sqk = fmaf(a.x, a.x, fmaf(a.y, a.y, fmaf(a.z, a.z, fmaf(a.w, a.w, sqk))));
        sqi = fmaf(b.x, b.x, fmaf(b.y, b.y, fmaf(b.z, b.z, fmaf(b.w, b.w, sqi))));
    }

    // wave (64-lane) shuffle reduce
#pragma unroll
    for (int off = 32; off > 0; off >>= 1) {
        dot += __shfl_down(dot, off);
        sqk += __shfl_down(sqk, off);
        sqi += __shfl_down(sqi, off);
    }

    __shared__ float s_dot[4], s_sqk[4], s_sqi[4];
    const int wave = t >> 6, lane = t & 63;
    if (lane == 0) { s_dot[wave] = dot; s_sqk[wave] = sqk; s_sqi[wave] = sqi; }
    __syncthreads();

    if (t == 0) {
        float dsum = s_dot[0] + s_dot[1] + s_dot[2] + s_dot[3];
        float ksum = s_sqk[0] + s_sqk[1] + s_sqk[2] + s_sqk[3];
        float isum = s_sqi[0] + s_sqi[1] + s_sqi[2] + s_sqi[3];
        float nk = fmaxf(sqrtf(ksum), EPS_COS);
        float ni = fmaxf(sqrtf(isum), EPS_COS);
        float cosv = dsum / (nk * ni);
        e_out[row] = expf(cosv * INV_TEMP);
    }
}

// Single block: sum e[0..n), exclude e[i], loss = -log(e[j] / (den + eps)).
__global__ __launch_bounds__(1024)
void loss_kernel(const float* __restrict__ e, const int* __restrict__ pos,
                 float* __restrict__ out, int n) {
    int i, j;
    get_ij(pos, n, i, j);
    const int t = threadIdx.x;

    float s = 0.f;
    for (int k = t; k < n; k += 1024) s += e[k];

#pragma unroll
    for (int off = 32; off > 0; off >>= 1) s += __shfl_down(s, off);

    __shared__ float ls[16];
    if ((t & 63) == 0) ls[t >> 6] = s;
    __syncthreads();

    if (t == 0) {
        float tot = 0.f;
#pragma unroll
        for (int w = 0; w < 16; ++w) tot += ls[w];
        float den = tot - e[i];
        float nom = e[j];
        out[0] = -logf(nom / (den + EPS_DEN));
    }
}

extern "C" void kernel_launch(void* const* d_in, const int* in_sizes, int n_in,
                              void* d_out, int out_size, void* d_ws, size_t ws_size,
                              hipStream_t stream) {
    const float* x   = (const float*)d_in[0];
    const int*   pos = (const int*)d_in[1];
    float*       out = (float*)d_out;
    float*       e   = (float*)d_ws;        // n floats of scratch

    const int n = in_sizes[0] / D;          // 16384

    row_kernel<<<n, 256, 0, stream>>>(x, pos, e, n);
    loss_kernel<<<1, 1024, 0, stream>>>(e, pos, out, n);
}